// Round 6
// baseline (77.137 us; speedup 1.0000x reference)
//
#include <hip/hip_runtime.h>

// Render_78907139162146: z-buffered triangle rasterizer, 256 tris -> 256x256 RGBA,
// bilinear sample from 3x1024x1024 uvmap.
//
// Scan semantics reduce per-pixel to: winner = last argmax of z (>= zmin, ties ->
// later index), zmin = global min vertex z. Associative over index-ordered
// chunks (later chunk wins ties via >=).
//
// R6: hot loop reads NO per-iteration LDS. The live-triangle stream is
// wave-uniform, so each wave preloads its chunk's (tt, ws) lane-parallel into
// VGPRs once, then per iteration v_readlane broadcasts them to SGPRs and the
// 9 triangle floats come via scalar loads from global tris (uniform address).
// Edge coefficients are re-derived in VALU with bit-identical expressions.
// This moves the 64B/iter record stream off the shared LDS pipe (32 waves/CU
// oversubscribed it ~4x vs per-SIMD VALU).
//
// Culling: y-bbox (row) + x-bbox (half-row window), margin 0.02 >> ~3e-6
// float edge-function rounding bound -> culled tris provably can't be
// float-inside for this block's pixels.
//
// Bit-exactness for survivors: no FMA contraction, exact op order,
// float64-internal linspace (np.linspace computes f64, casts f32).

#define S 256
#define TMAX 256
#define NC 8       // triangle chunks per block
#define BT 1024    // threads per block (16 waves)
#define HALF 128   // pixels per block (half row)
#define MARGIN 0.02f

__global__ __launch_bounds__(BT) void render_kernel(
    const float* __restrict__ tris,
    const float* __restrict__ uvs,
    const float* __restrict__ uvmap,
    float* __restrict__ out,
    int T)
{
#pragma clang fp contract(off)
    __shared__ int    list[TMAX];    // compacted live triangle indices
    __shared__ float  wsl[TMAX];     // their ws (= w, valid guaranteed)
    __shared__ unsigned long long masks[4];
    __shared__ float  zpart[4];
    __shared__ float4 cand[NC][HALF];   // z, w1, w2, win

    const int tid  = threadIdx.x;
    const int bid  = blockIdx.x;
    const int row  = bid >> 1;          // output row
    const int half = bid & 1;           // which half of the row
    const int j    = half * HALF + (tid & (HALF - 1));   // output col
    const int c    = tid >> 7;          // chunk 0..7 (uniform per wave)
    const int lane = tid & 63;

    // pts[row,j] = (lin[j], lin[255-row]); np.linspace computes f64, casts f32.
    const float px = (float)(-1.0 + (double)j * (2.0 / 255.0));
    const float py = (float)(-1.0 + (double)(S - 1 - row) * (2.0 / 255.0));
    // block x-window (inclusive pixel extremes of this half-row)
    const float pxlo = (float)(-1.0 + (double)(half * HALF) * (2.0 / 255.0));
    const float pxhi = (float)(-1.0 + (double)(half * HALF + HALF - 1) * (2.0 / 255.0));

    // ---- cull flags + per-wave zmin (waves 0..3, one triangle per thread) ----
    bool keep = false;
    float zl = 3.0e38f;
    float wq = 1.0f;
    if (tid < TMAX && tid < T) {
        const float* p = tris + tid * 9;
        float Ax = p[0], Ay = p[1], Az = p[2];
        float Bx = p[3], By = p[4], Bz = p[5];
        float Cx = p[6], Cy = p[7], Cz = p[8];
        float w = (Bx - Ax) * (Cy - Ay) - (By - Ay) * (Cx - Ax);
        bool valid = (w >= 1e-9f);
        wq = w;
        zl = fminf(Az, fminf(Bz, Cz));
        float ymn = fminf(Ay, fminf(By, Cy));
        float ymx = fmaxf(Ay, fmaxf(By, Cy));
        float xmn = fminf(Ax, fminf(Bx, Cx));
        float xmx = fmaxf(Ax, fmaxf(Bx, Cx));
        keep = valid && (py >= ymn - MARGIN) && (py <= ymx + MARGIN)
                     && (pxhi >= xmn - MARGIN) && (pxlo <= xmx + MARGIN);
    }
    unsigned long long m = __ballot(keep);
    if (tid < TMAX) {
        float zw = zl;
        #pragma unroll
        for (int o = 32; o > 0; o >>= 1) zw = fminf(zw, __shfl_xor(zw, o, 64));
        if (lane == 0) { masks[tid >> 6] = m; zpart[tid >> 6] = zw; }
    }
    __syncthreads();   // barrier 1: masks, zpart visible

    // every thread computes prefix offsets locally (4 popcnts, no barrier)
    const int n0 = __popcll(masks[0]);
    const int n1 = __popcll(masks[1]);
    const int n2 = __popcll(masks[2]);
    const int n3 = __popcll(masks[3]);
    const int nlive = n0 + n1 + n2 + n3;
    const float zmin = fminf(fminf(zpart[0], zpart[1]), fminf(zpart[2], zpart[3]));

    // order-preserving compaction (waves 0..3)
    if (tid < TMAX && keep) {
        int wv  = tid >> 6;
        int off = (wv > 0 ? n0 : 0) + (wv > 1 ? n1 : 0) + (wv > 2 ? n2 : 0);
        int pos = off + __popcll(masks[wv] & ((1ull << lane) - 1ull));
        list[pos] = tid;
        wsl[pos]  = wq;
    }
    __syncthreads();   // barrier 2: list/wsl visible

    // ---- per-pixel rasterization over this chunk's slice of the live list ----
    const int cs = (nlive + NC - 1) / NC;
    const int tb = c * cs;
    int cnt = nlive - tb;
    if (cnt > cs) cnt = cs;
    if (cnt < 0)  cnt = 0;

    // wave-preload this chunk's (tt, ws) lane-parallel; readlane-broadcast later
    int lidx = tb + lane;
    if (lidx > TMAX - 1) lidx = TMAX - 1;
    const int   vtt = list[lidx];
    const float vws = wsl[lidx];

    float zcur = zmin;
    int win = -1;
    float w1w = 0.0f, w2w = 0.0f;

    for (int it = 0; it < cnt; ++it) {
        const int   tt = __builtin_amdgcn_readlane(vtt, it);                    // SGPR
        const float ws = __int_as_float(__builtin_amdgcn_readlane(__float_as_int(vws), it));
        const float* p = tris + tt * 9;          // uniform address -> scalar loads
        float Ax = p[0], Ay = p[1], Az = p[2];
        float Bx = p[3], By = p[4], Bz = p[5];
        float Cx = p[6], Cy = p[7], Cz = p[8];
        // bit-identical to reference _area2d op order
        float pAB = (px - Bx) * (Ay - By) - (py - By) * (Ax - Bx);
        float pCB = (px - Cx) * (By - Cy) - (py - Cy) * (Bx - Cx);
        float pCA = (px - Ax) * (Cy - Ay) - (py - Ay) * (Cx - Ax);
        float prod = fmaxf(pAB, 0.0f) * fmaxf(pCB, 0.0f) * fmaxf(pCA, 0.0f);
        if (prod > 0.0f) {
            float w1 = pCB / ws;
            float w2 = pCA / ws;
            float w3 = (1.0f - w1) - w2;
            float z = (w1 * Az + w2 * Bz) + w3 * Cz;
            if (z >= zcur) { zcur = z; win = tt; w1w = w1; w2w = w2; }
        }
    }
    cand[c][tid & (HALF - 1)] = make_float4(zcur, w1w, w2w, (float)win);
    __syncthreads();   // barrier 3: cand visible

    // ---- merge chunk candidates (ascending chunk = ascending tri index; >= = later wins) ----
    if (tid < HALF) {
        float zb = 0.0f, w1 = 0.0f, w2 = 0.0f;
        int w = -1;
        #pragma unroll
        for (int k = 0; k < NC; ++k) {
            float4 ck = cand[k][tid];
            int cw = (int)ck.w;
            if (cw >= 0 && (w < 0 || ck.x >= zb)) {
                zb = ck.x; w1 = ck.y; w2 = ck.z; w = cw;
            }
        }

        // ---- epilogue: bilinear texture sample for the winning triangle ----
        float r = 0.0f, g = 0.0f, b = 0.0f, a = 0.0f;
        if (w >= 0) {
            a = 1.0f;
            float w3 = (1.0f - w1) - w2;
            const float* q = uvs + w * 6;        // divergent winner -> vector loads
            float u0x = q[0] * 2.0f - 1.0f, u0y = q[1] * 2.0f - 1.0f;
            float u1x = q[2] * 2.0f - 1.0f, u1y = q[3] * 2.0f - 1.0f;
            float u2x = q[4] * 2.0f - 1.0f, u2y = q[5] * 2.0f - 1.0f;
            float ux = (w1 * u0x + w2 * u1x) + w3 * u2x;
            float uy = (w1 * u0y + w2 * u1y) + w3 * u2y;
            float X = ((ux + 1.0f) * 0.5f) * 1023.0f;
            float Y = ((uy + 1.0f) * 0.5f) * 1023.0f;
            float x0 = floorf(X), y0 = floorf(Y);
            float wx = X - x0, wy = Y - y0;
            float w00 = (1.0f - wx) * (1.0f - wy);
            float w10 = wx * (1.0f - wy);
            float w01 = (1.0f - wx) * wy;
            float w11 = wx * wy;
            float xs1 = x0 + 1.0f, ys1 = y0 + 1.0f;
            bool xin0 = (x0  >= 0.0f) && (x0  <= 1023.0f);
            bool xin1 = (xs1 >= 0.0f) && (xs1 <= 1023.0f);
            bool yin0 = (y0  >= 0.0f) && (y0  <= 1023.0f);
            bool yin1 = (ys1 >= 0.0f) && (ys1 <= 1023.0f);
            int xi0 = (int)fminf(fmaxf(x0,  0.0f), 1023.0f);
            int xi1 = (int)fminf(fmaxf(xs1, 0.0f), 1023.0f);
            int yi0 = (int)fminf(fmaxf(y0,  0.0f), 1023.0f);
            int yi1 = (int)fminf(fmaxf(ys1, 0.0f), 1023.0f);
            float acc[3];
            #pragma unroll
            for (int ch = 0; ch < 3; ++ch) {
                const float* img = uvmap + ch * (1024 * 1024);
                float v00 = (xin0 && yin0) ? img[yi0 * 1024 + xi0] : 0.0f;
                float v10 = (xin1 && yin0) ? img[yi0 * 1024 + xi1] : 0.0f;
                float v01 = (xin0 && yin1) ? img[yi1 * 1024 + xi0] : 0.0f;
                float v11 = (xin1 && yin1) ? img[yi1 * 1024 + xi1] : 0.0f;
                acc[ch] = ((v00 * w00 + v10 * w10) + v01 * w01) + v11 * w11;
            }
            r = acc[0]; g = acc[1]; b = acc[2];
        }

        const int base = row * S + j;
        out[0 * S * S + base] = r;
        out[1 * S * S + base] = g;
        out[2 * S * S + base] = b;
        out[3 * S * S + base] = a;
    }
}

extern "C" void kernel_launch(void* const* d_in, const int* in_sizes, int n_in,
                              void* d_out, int out_size, void* d_ws, size_t ws_size,
                              hipStream_t stream) {
    const float* tris  = (const float*)d_in[0];
    const float* uvs   = (const float*)d_in[1];
    const float* uvmap = (const float*)d_in[2];
    float* out = (float*)d_out;
    int T = in_sizes[0] / 9;
    if (T > TMAX) T = TMAX;
    render_kernel<<<dim3(2 * S), dim3(BT), 0, stream>>>(tris, uvs, uvmap, out, T);
}

// Round 7
// 77.106 us; speedup vs baseline: 1.0004x; 1.0004x over previous
//
#include <hip/hip_runtime.h>

// Render_78907139162146: z-buffered triangle rasterizer, 256 tris -> 256x256 RGBA,
// bilinear sample from 3x1024x1024 uvmap.
//
// Scan semantics reduce per-pixel to: winner = last argmax of z (>= zmin, ties ->
// later index), zmin = global min vertex z. Associative over index-ordered
// chunks (later chunk wins ties via >=).
//
// R7: wave-level scalar bbox skip in the hot loop. Each live triangle's x-bbox
// is preloaded lane-parallel with (tt, ws); per iteration readlane broadcasts
// to SGPRs and an s_cmp/s_cbranch against THIS WAVE's 64-px x-window skips the
// whole 28-op VALU body (~35-40% of survivors: block window is 1.0 NDC, wave
// window 0.5). Margin 0.005 >> ~3e-6 float edge-function rounding bound, so a
// skipped triangle provably can't be float-inside for any lane of the wave.
//
// History: R2 block=1024/4-chunk 89us; R3 2-kernel split REGRESSED (launch
// cost > s_load win); R4 half-row blocks + y/x block cull 78.3; R5 shfl zmin
// (3 barriers) 76.8; R6 scalar-load records NEUTRAL (loop not LDS/VALU bound).
//
// Bit-exactness for survivors: no FMA contraction, exact op order,
// float64-internal linspace (np.linspace computes f64, casts f32).

#define S 256
#define TMAX 256
#define NC 8       // triangle chunks per block
#define BT 1024    // threads per block (16 waves)
#define HALF 128   // pixels per block (half row)
#define MARGIN 0.005f

__global__ __launch_bounds__(BT) void render_kernel(
    const float* __restrict__ tris,
    const float* __restrict__ uvs,
    const float* __restrict__ uvmap,
    float* __restrict__ out,
    int T)
{
#pragma clang fp contract(off)
    __shared__ int    list[TMAX];    // compacted live triangle indices
    __shared__ float  wsl[TMAX];     // their ws (= w, valid guaranteed)
    __shared__ float  xmnl[TMAX];    // their x-bbox min
    __shared__ float  xmxl[TMAX];    // their x-bbox max
    __shared__ unsigned long long masks[4];
    __shared__ float  zpart[4];
    __shared__ float4 cand[NC][HALF];   // z, w1, w2, win

    const int tid  = threadIdx.x;
    const int bid  = blockIdx.x;
    const int row  = bid >> 1;          // output row
    const int half = bid & 1;           // which half of the row
    const int j    = half * HALF + (tid & (HALF - 1));   // output col
    const int c    = tid >> 7;          // chunk 0..7 (uniform per wave)
    const int lane = tid & 63;

    // pts[row,j] = (lin[j], lin[255-row]); np.linspace computes f64, casts f32.
    const float px = (float)(-1.0 + (double)j * (2.0 / 255.0));
    const float py = (float)(-1.0 + (double)(S - 1 - row) * (2.0 / 255.0));
    // block x-window (inclusive pixel extremes of this half-row)
    const float pxlo = (float)(-1.0 + (double)(half * HALF) * (2.0 / 255.0));
    const float pxhi = (float)(-1.0 + (double)(half * HALF + HALF - 1) * (2.0 / 255.0));
    // this wave's 64-px x-window (wave-uniform)
    const int   wbase = half * HALF + ((tid >> 6) & 1) * 64;
    const float wlo = (float)(-1.0 + (double)wbase * (2.0 / 255.0));
    const float whi = (float)(-1.0 + (double)(wbase + 63) * (2.0 / 255.0));

    // ---- cull flags + per-wave zmin (waves 0..3, one triangle per thread) ----
    bool keep = false;
    float zl = 3.0e38f;
    float wq = 1.0f, xmnq = 0.0f, xmxq = 0.0f;
    if (tid < TMAX && tid < T) {
        const float* p = tris + tid * 9;
        float Ax = p[0], Ay = p[1], Az = p[2];
        float Bx = p[3], By = p[4], Bz = p[5];
        float Cx = p[6], Cy = p[7], Cz = p[8];
        float w = (Bx - Ax) * (Cy - Ay) - (By - Ay) * (Cx - Ax);
        bool valid = (w >= 1e-9f);
        wq = w;
        zl = fminf(Az, fminf(Bz, Cz));
        float ymn = fminf(Ay, fminf(By, Cy));
        float ymx = fmaxf(Ay, fmaxf(By, Cy));
        xmnq = fminf(Ax, fminf(Bx, Cx));
        xmxq = fmaxf(Ax, fmaxf(Bx, Cx));
        keep = valid && (py >= ymn - MARGIN) && (py <= ymx + MARGIN)
                     && (pxhi >= xmnq - MARGIN) && (pxlo <= xmxq + MARGIN);
    }
    unsigned long long m = __ballot(keep);
    if (tid < TMAX) {
        float zw = zl;
        #pragma unroll
        for (int o = 32; o > 0; o >>= 1) zw = fminf(zw, __shfl_xor(zw, o, 64));
        if (lane == 0) { masks[tid >> 6] = m; zpart[tid >> 6] = zw; }
    }
    __syncthreads();   // barrier 1: masks, zpart visible

    // every thread computes prefix offsets locally (4 popcnts, no barrier)
    const int n0 = __popcll(masks[0]);
    const int n1 = __popcll(masks[1]);
    const int n2 = __popcll(masks[2]);
    const int n3 = __popcll(masks[3]);
    const int nlive = n0 + n1 + n2 + n3;
    const float zmin = fminf(fminf(zpart[0], zpart[1]), fminf(zpart[2], zpart[3]));

    // order-preserving compaction (waves 0..3)
    if (tid < TMAX && keep) {
        int wv  = tid >> 6;
        int off = (wv > 0 ? n0 : 0) + (wv > 1 ? n1 : 0) + (wv > 2 ? n2 : 0);
        int pos = off + __popcll(masks[wv] & ((1ull << lane) - 1ull));
        list[pos] = tid;
        wsl[pos]  = wq;
        xmnl[pos] = xmnq;
        xmxl[pos] = xmxq;
    }
    __syncthreads();   // barrier 2: list/wsl/bbox visible

    // ---- per-pixel rasterization over this chunk's slice of the live list ----
    const int cs = (nlive + NC - 1) / NC;
    const int tb = c * cs;
    int cnt = nlive - tb;
    if (cnt > cs) cnt = cs;
    if (cnt < 0)  cnt = 0;

    // wave-preload this chunk's (tt, ws, bbox) lane-parallel; readlane later
    int lidx = tb + lane;
    if (lidx > TMAX - 1) lidx = TMAX - 1;
    const int   vtt  = list[lidx];
    const float vws  = wsl[lidx];
    const float vxmn = xmnl[lidx];
    const float vxmx = xmxl[lidx];

    float zcur = zmin;
    int win = -1;
    float w1w = 0.0f, w2w = 0.0f;

    for (int it = 0; it < cnt; ++it) {
        // wave-uniform scalar bbox test: skip the whole VALU body if this
        // triangle can't touch this wave's 64-px window (margin soundness).
        const float xmn = __int_as_float(__builtin_amdgcn_readlane(__float_as_int(vxmn), it));
        const float xmx = __int_as_float(__builtin_amdgcn_readlane(__float_as_int(vxmx), it));
        if (whi < xmn - MARGIN || wlo > xmx + MARGIN) continue;

        const int   tt = __builtin_amdgcn_readlane(vtt, it);                    // SGPR
        const float ws = __int_as_float(__builtin_amdgcn_readlane(__float_as_int(vws), it));
        const float* p = tris + tt * 9;          // uniform address -> scalar loads
        float Ax = p[0], Ay = p[1], Az = p[2];
        float Bx = p[3], By = p[4], Bz = p[5];
        float Cx = p[6], Cy = p[7], Cz = p[8];
        // bit-identical to reference _area2d op order
        float pAB = (px - Bx) * (Ay - By) - (py - By) * (Ax - Bx);
        float pCB = (px - Cx) * (By - Cy) - (py - Cy) * (Bx - Cx);
        float pCA = (px - Ax) * (Cy - Ay) - (py - Ay) * (Cx - Ax);
        float prod = fmaxf(pAB, 0.0f) * fmaxf(pCB, 0.0f) * fmaxf(pCA, 0.0f);
        if (prod > 0.0f) {
            float w1 = pCB / ws;
            float w2 = pCA / ws;
            float w3 = (1.0f - w1) - w2;
            float z = (w1 * Az + w2 * Bz) + w3 * Cz;
            if (z >= zcur) { zcur = z; win = tt; w1w = w1; w2w = w2; }
        }
    }
    cand[c][tid & (HALF - 1)] = make_float4(zcur, w1w, w2w, (float)win);
    __syncthreads();   // barrier 3: cand visible

    // ---- merge chunk candidates (ascending chunk = ascending tri index; >= = later wins) ----
    if (tid < HALF) {
        float zb = 0.0f, w1 = 0.0f, w2 = 0.0f;
        int w = -1;
        #pragma unroll
        for (int k = 0; k < NC; ++k) {
            float4 ck = cand[k][tid];
            int cw = (int)ck.w;
            if (cw >= 0 && (w < 0 || ck.x >= zb)) {
                zb = ck.x; w1 = ck.y; w2 = ck.z; w = cw;
            }
        }

        // ---- epilogue: bilinear texture sample for the winning triangle ----
        float r = 0.0f, g = 0.0f, b = 0.0f, a = 0.0f;
        if (w >= 0) {
            a = 1.0f;
            float w3 = (1.0f - w1) - w2;
            const float* q = uvs + w * 6;        // divergent winner -> vector loads
            float u0x = q[0] * 2.0f - 1.0f, u0y = q[1] * 2.0f - 1.0f;
            float u1x = q[2] * 2.0f - 1.0f, u1y = q[3] * 2.0f - 1.0f;
            float u2x = q[4] * 2.0f - 1.0f, u2y = q[5] * 2.0f - 1.0f;
            float ux = (w1 * u0x + w2 * u1x) + w3 * u2x;
            float uy = (w1 * u0y + w2 * u1y) + w3 * u2y;
            float X = ((ux + 1.0f) * 0.5f) * 1023.0f;
            float Y = ((uy + 1.0f) * 0.5f) * 1023.0f;
            float x0 = floorf(X), y0 = floorf(Y);
            float wx = X - x0, wy = Y - y0;
            float w00 = (1.0f - wx) * (1.0f - wy);
            float w10 = wx * (1.0f - wy);
            float w01 = (1.0f - wx) * wy;
            float w11 = wx * wy;
            float xs1 = x0 + 1.0f, ys1 = y0 + 1.0f;
            bool xin0 = (x0  >= 0.0f) && (x0  <= 1023.0f);
            bool xin1 = (xs1 >= 0.0f) && (xs1 <= 1023.0f);
            bool yin0 = (y0  >= 0.0f) && (y0  <= 1023.0f);
            bool yin1 = (ys1 >= 0.0f) && (ys1 <= 1023.0f);
            int xi0 = (int)fminf(fmaxf(x0,  0.0f), 1023.0f);
            int xi1 = (int)fminf(fmaxf(xs1, 0.0f), 1023.0f);
            int yi0 = (int)fminf(fmaxf(y0,  0.0f), 1023.0f);
            int yi1 = (int)fminf(fmaxf(ys1, 0.0f), 1023.0f);
            float acc[3];
            #pragma unroll
            for (int ch = 0; ch < 3; ++ch) {
                const float* img = uvmap + ch * (1024 * 1024);
                float v00 = (xin0 && yin0) ? img[yi0 * 1024 + xi0] : 0.0f;
                float v10 = (xin1 && yin0) ? img[yi0 * 1024 + xi1] : 0.0f;
                float v01 = (xin0 && yin1) ? img[yi1 * 1024 + xi0] : 0.0f;
                float v11 = (xin1 && yin1) ? img[yi1 * 1024 + xi1] : 0.0f;
                acc[ch] = ((v00 * w00 + v10 * w10) + v01 * w01) + v11 * w11;
            }
            r = acc[0]; g = acc[1]; b = acc[2];
        }

        const int base = row * S + j;
        out[0 * S * S + base] = r;
        out[1 * S * S + base] = g;
        out[2 * S * S + base] = b;
        out[3 * S * S + base] = a;
    }
}

extern "C" void kernel_launch(void* const* d_in, const int* in_sizes, int n_in,
                              void* d_out, int out_size, void* d_ws, size_t ws_size,
                              hipStream_t stream) {
    const float* tris  = (const float*)d_in[0];
    const float* uvs   = (const float*)d_in[1];
    const float* uvmap = (const float*)d_in[2];
    float* out = (float*)d_out;
    int T = in_sizes[0] / 9;
    if (T > TMAX) T = TMAX;
    render_kernel<<<dim3(2 * S), dim3(BT), 0, stream>>>(tris, uvs, uvmap, out, T);
}